// Round 5
// baseline (163.041 us; speedup 1.0000x reference)
//
#include <hip/hip_runtime.h>
#include <cstdint>

#define B_DIM 32
#define T_DIM 1024
#define NIN 128
#define NG 16       // i-groups of 8
#define NHID 1024
#define KSLOT 8
#define NWORDS 34   // 2 guard words (64 zero bits) + 32 data words
#define WAVES 8
#define CHUNKS 32
#define PAIRS (CHUNKS / 2)
#define ROUNDS (PAIRS / WAVES)
#define WSCALE 16.0f

// Incremental-mask ladder (R17): prefix masks {0x11,0x33,0x77,none}; per-t
// currents recovered by integer differencing (bit-exact vs bit-plane accs).
#define SC0 (1.0f / 16.0f)
#define SC1 (1.0f / 32.0f)
#define SC2 (1.0f / 64.0f)
#define SC3 (-1.0f / 128.0f)
// 0.9^64, double-computed then float-rounded (fast-path only; drift contracts)
#define P64 0.0011790184577738599f

// 8 x i4 MAC in one instruction (v_dot8_i32_i4). Fallback preserves semantics.
__device__ __forceinline__ int dot8acc(uint32_t sel, uint32_t wq, int acc) {
#if __has_builtin(__builtin_amdgcn_sdot8)
    return __builtin_amdgcn_sdot8((int)sel, (int)wq, acc, false);
#else
    #pragma unroll
    for (int m = 0; m < 8; ++m) {
        int s = ((int)((sel >> (4 * m)) & 0xF) << 28) >> 28;   // signed i4
        int q = ((int)((wq  >> (4 * m)) & 0xF) << 28) >> 28;   // signed i4
        acc += s * q;
    }
    return acc;
#endif
}

__device__ __forceinline__ uint32_t permb(uint32_t hi, uint32_t lo, uint32_t sel) {
#if __has_builtin(__builtin_amdgcn_perm)
    return __builtin_amdgcn_perm(hi, lo, sel);   // S0=hi(bytes 7..4), S1=lo(bytes 3..0)
#else
    union { uint32_t w[2]; unsigned char b[8]; } src;
    src.w[0] = lo; src.w[1] = hi;
    uint32_t r = 0;
    for (int n = 0; n < 4; ++n) r |= (uint32_t)src.b[(sel >> (8 * n)) & 7] << (8 * n);
    return r;
#endif
}

__device__ __forceinline__ uint32_t funnel32(uint32_t hi, uint32_t lo, uint32_t sh) {
#if __has_builtin(__builtin_amdgcn_alignbit)
    return __builtin_amdgcn_alignbit(hi, lo, sh);   // ((hi:lo) >> (sh&31)) low 32
#else
    return (uint32_t)(((((uint64_t)hi) << 32) | lo) >> (sh & 31));
#endif
}

// ---------------- merged prep kernel ----------------
// blocks   0..511: pack spike bits TRANSPOSED: xbitsT[b][w][i]
// blocks 512..575: packed per-(g,h) params: {sp bytes lo, sp bytes hi, wq nibbles, pad}
//                  (sp = 63 - delay; wq nibble order [0,4,1,5,2,6,3,7])
// blocks 576..580: init out (logits = bias, totals = 0)
__global__ void prep_kernel(const float* __restrict__ x, const float* __restrict__ W,
                            const float* __restrict__ draw, const float* __restrict__ b_ro,
                            uint32_t* __restrict__ xbitsT, uint4* __restrict__ pk4,
                            float* __restrict__ out) {
    int blk = blockIdx.x, tid = threadIdx.x;
    if (blk < 512) {
        int idx = blk * 256 + tid;        // 131072 = b*4096 + w*128 + i
        int b = idx >> 12, w = (idx >> 7) & 31, i = idx & 127;
        const float* xp = x + (size_t)b * T_DIM * NIN + (size_t)w * 32 * NIN + i;
        uint32_t word = 0;
        #pragma unroll
        for (int bit = 0; bit < 32; ++bit) {
            float xv = xp[(size_t)bit * NIN];   // lanes = consecutive i -> coalesced
            word |= (xv != 0.0f) ? (1u << bit) : 0u;
        }
        uint32_t* bp = xbitsT + (size_t)b * NWORDS * NIN;
        bp[(2 + w) * NIN + i] = word;           // transposed: [w][i]
        if (w == 0) { bp[i] = 0u; bp[NIN + i] = 0u; }   // guard rows
    } else if (blk < 576) {
        int idx = (blk - 512) * 256 + tid;    // 16384 = g*1024 + h
        int g = idx >> 10, h = idx & 1023;
        const float* Wp = W    + (size_t)h * NIN + 8 * g;
        const float* Rp = draw + (size_t)h * NIN + 8 * g;
        uint32_t s0 = 0, s1 = 0, wq = 0;
        const int ordm[8] = {0, 4, 1, 5, 2, 6, 3, 7};
        #pragma unroll
        for (int j = 0; j < 4; ++j) {
            int sp_a = 63 - (int)rintf(50.0f / (1.0f + expf(-Rp[j])));      // RNE = jnp.round
            int sp_b = 63 - (int)rintf(50.0f / (1.0f + expf(-Rp[4 + j])));
            s0 |= (uint32_t)sp_a << (8 * j);
            s1 |= (uint32_t)sp_b << (8 * j);
        }
        #pragma unroll
        for (int m = 0; m < 8; ++m) {
            int q = (int)rintf(fminf(fmaxf(Wp[ordm[m]] * WSCALE, -8.0f), 7.0f));
            wq |= ((uint32_t)q & 0xFu) << (4 * m);
        }
        pk4[(size_t)g * NHID + h] = make_uint4(s0, s1, wq, 0u);
    } else {
        int idx = (blk - 576) * 256 + tid;    // 1280 outputs
        if (idx < B_DIM * KSLOT) out[idx] = b_ro[0];
        else if (idx < B_DIM * KSLOT + T_DIM) out[idx] = 0.0f;
    }
}

// prefix-mask quad: 3 ands + 4 dots (was 4 ands + 4 dots)
#define QUAD4(X, ACC, BASE, WQ)                                                 \
    ACC[(BASE)+0] = dot8acc((X) & 0x11111111u, WQ, ACC[(BASE)+0]);              \
    ACC[(BASE)+1] = dot8acc((X) & 0x33333333u, WQ, ACC[(BASE)+1]);              \
    ACC[(BASE)+2] = dot8acc((X) & 0x77777777u, WQ, ACC[(BASE)+2]);              \
    ACC[(BASE)+3] = dot8acc((X),               WQ, ACC[(BASE)+3]);

// mask-ladder: 8 windows (one 32-t word per stream) -> 32 prefix dots via sdot8.
#define LADDER(W_, ACC, WQ)                                                     \
    {                                                                           \
        uint32_t A0 = permb(W_[1], W_[0], 0x05010400u);                         \
        uint32_t B0 = permb(W_[1], W_[0], 0x07030602u);                         \
        uint32_t C0 = permb(W_[3], W_[2], 0x05010400u);                         \
        uint32_t D0 = permb(W_[3], W_[2], 0x07030602u);                         \
        uint32_t A1 = permb(W_[5], W_[4], 0x05010400u);                         \
        uint32_t B1 = permb(W_[5], W_[4], 0x07030602u);                         \
        uint32_t C1 = permb(W_[7], W_[6], 0x05010400u);                         \
        uint32_t D1 = permb(W_[7], W_[6], 0x07030602u);                         \
        {                                                                       \
            uint32_t P = permb(C0, A0, 0x05040100u);                            \
            uint32_t Q = permb(C1, A1, 0x05040100u);                            \
            uint32_t X0 = (P & 0x0F0F0F0Fu) | ((Q << 4) & 0xF0F0F0F0u);         \
            uint32_t X1 = ((P >> 4) & 0x0F0F0F0Fu) | (Q & 0xF0F0F0F0u);         \
            QUAD4(X0, ACC, 0, WQ)                                               \
            QUAD4(X1, ACC, 4, WQ)                                               \
        }                                                                       \
        {                                                                       \
            uint32_t P = permb(C0, A0, 0x07060302u);                            \
            uint32_t Q = permb(C1, A1, 0x07060302u);                            \
            uint32_t X2 = (P & 0x0F0F0F0Fu) | ((Q << 4) & 0xF0F0F0F0u);         \
            uint32_t X3 = ((P >> 4) & 0x0F0F0F0Fu) | (Q & 0xF0F0F0F0u);         \
            QUAD4(X2, ACC, 8, WQ)                                               \
            QUAD4(X3, ACC, 12, WQ)                                              \
        }                                                                       \
        {                                                                       \
            uint32_t P = permb(D0, B0, 0x05040100u);                            \
            uint32_t Q = permb(D1, B1, 0x05040100u);                            \
            uint32_t X4 = (P & 0x0F0F0F0Fu) | ((Q << 4) & 0xF0F0F0F0u);         \
            uint32_t X5 = ((P >> 4) & 0x0F0F0F0Fu) | (Q & 0xF0F0F0F0u);         \
            QUAD4(X4, ACC, 16, WQ)                                              \
            QUAD4(X5, ACC, 20, WQ)                                              \
        }                                                                       \
        {                                                                       \
            uint32_t P = permb(D0, B0, 0x07060302u);                            \
            uint32_t Q = permb(D1, B1, 0x07060302u);                            \
            uint32_t X6 = (P & 0x0F0F0F0Fu) | ((Q << 4) & 0xF0F0F0F0u);         \
            uint32_t X7 = ((P >> 4) & 0x0F0F0F0Fu) | (Q & 0xF0F0F0F0u);         \
            QUAD4(X6, ACC, 24, WQ)                                              \
            QUAD4(X7, ACC, 28, WQ)                                              \
        }                                                                       \
    }

// build both pair-windows for 4 streams from 4 row-quads + packed sp byte word
#define BUILD4(SPW, R0, R1, R2, R3, WL, WH, BASE)                               \
    {                                                                           \
        uint32_t sp0 = (SPW) & 0xFFu;                                           \
        uint32_t sp1 = ((SPW) >> 8) & 0xFFu;                                    \
        uint32_t sp2 = ((SPW) >> 16) & 0xFFu;                                   \
        uint32_t sp3 = (SPW) >> 24;                                             \
        bool se0 = sp0 >= 32u, se1 = sp1 >= 32u, se2 = sp2 >= 32u, se3 = sp3 >= 32u; \
        uint32_t a0 = se0 ? R1.x : R0.x, m0 = se0 ? R2.x : R1.x, c0 = se0 ? R3.x : R2.x; \
        uint32_t a1 = se1 ? R1.y : R0.y, m1 = se1 ? R2.y : R1.y, c1 = se1 ? R3.y : R2.y; \
        uint32_t a2 = se2 ? R1.z : R0.z, m2 = se2 ? R2.z : R1.z, c2 = se2 ? R3.z : R2.z; \
        uint32_t a3 = se3 ? R1.w : R0.w, m3 = se3 ? R2.w : R1.w, c3 = se3 ? R3.w : R2.w; \
        WL[BASE + 0] = funnel32(m0, a0, sp0); WH[BASE + 0] = funnel32(c0, m0, sp0); \
        WL[BASE + 1] = funnel32(m1, a1, sp1); WH[BASE + 1] = funnel32(c1, m1, sp1); \
        WL[BASE + 2] = funnel32(m2, a2, sp2); WH[BASE + 2] = funnel32(c2, m2, sp2); \
        WL[BASE + 3] = funnel32(m3, a3, sp3); WH[BASE + 3] = funnel32(c3, m3, sp3); \
    }

// pre-token affine accumulation over one 32-acc half:
// S_t = 0.9*S_{t-1} + 0.1*I_t (v-independent), mS = max_t S_t.
// Runs BEFORE the relay token arrives -> off the serial chain.
#define PRES32(A)                                                               \
    _Pragma("unroll")                                                           \
    for (int q = 0; q < 8; ++q) {                                               \
        int a0 = A[4*q], a1 = A[4*q+1], a2 = A[4*q+2], a3 = A[4*q+3];           \
        float s0, s1, s2, s3;                                                   \
        S = fmaf(0.9f, S, (float)a0        * (0.1f * SC0)); s0 = S;             \
        S = fmaf(0.9f, S, (float)(a1 - a0) * (0.1f * SC1)); s1 = S;             \
        S = fmaf(0.9f, S, (float)(a2 - a1) * (0.1f * SC2)); s2 = S;             \
        S = fmaf(0.9f, S, (float)(a3 - a2) * (0.1f * SC3)); s3 = S;             \
        mS = fmaxf(mS, fmaxf(fmaxf(s0, s1), fmaxf(s2, s3)));                    \
    }

// exact-path LIF over one 32-acc half (rare), prefix-diff recovery, bit-exact.
#define SLOW32(A, TBASE)                                                        \
    _Pragma("unroll")                                                           \
    for (int q = 0; q < 8; ++q) {                                               \
        int a0 = A[4*q], a1 = A[4*q+1], a2 = A[4*q+2], a3 = A[4*q+3];           \
        _Pragma("unroll")                                                       \
        for (int j = 0; j < 4; ++j) {                                           \
            float I = (j == 0) ? (float)a0        * SC0                         \
                    : (j == 1) ? (float)(a1 - a0) * SC1                         \
                    : (j == 2) ? (float)(a2 - a1) * SC2                         \
                    :            (float)(a3 - a2) * SC3;                        \
            int t = (TBASE) + 4 * q + j;                                        \
            bool active = (rf <= 0.0f);                                         \
            float vupd = v + 0.1f * (I - v);                                    \
            float vn = active ? vupd : v;                                       \
            bool spike = active && (vn >= 1.0f);                                \
            unsigned long long bal = __ballot(spike);                           \
            if (bal != 0ULL) {                                                  \
                if (spike) {                                                    \
                    vn = 0.0f;                /* V_RESET */                     \
                    _Pragma("unroll")                                           \
                    for (int k2 = 0; k2 < KSLOT; ++k2)                          \
                        if (t >= st_[k2] && t < en_[k2]) sacc[k2] += 1.0f;      \
                }                                                               \
                rf = spike ? 2.0f : fmaxf(rf - 1.0f, 0.0f);                     \
                if (lane == 0) atomicAdd(&out[B_DIM * KSLOT + t], (float)__popcll(bal)); \
            } else {                                                            \
                rf = fmaxf(rf - 1.0f, 0.0f);                                    \
            }                                                                   \
            v = vn;                                                             \
        }                                                                       \
    }

// ---------------- fused sdot8 mask-ladder + wave-relay LIF ----------------
// block = (b, hg of 64 h), 512 threads = 8 waves, grid 512.
// R18 = R17 (81 us) + affine hoist of the LIF fast path OFF the relay chain.
// Post-mortems: R14 occupancy x2 neutral, R16 ILP neutral, R15/R17 inst cuts
// pay ~1:1 -> residual 26% idle is the SERIAL token chain, whose per-link cost
// was the 64-step dependent-FMA recurrence (starts from v_in). Linearity:
// v_t = 0.9^t*v_in + S_t with S_t v-independent -> compute S, mS = max_t S_t
// BEFORE the token (parallel across waves). Token-critical section becomes:
// sound spike test (rf>0 || max(v,0)+mS >= 0.999) + v = fma(0.9^64, v, S).
// Slow path (never fires in practice, >=7 sigma) stays bit-exact from v_in.
// fp drift in v contracts x0.00118/pair and v is internal; outputs unchanged.
// s_setprio(1) wraps the critical link (T5: role diversity exists here).
__global__ __launch_bounds__(512, 4) void fused_kernel(
    const uint4* __restrict__ pk4, const uint32_t* __restrict__ xbitsT,
    float* __restrict__ out, const float* __restrict__ w_ro,
    const int* __restrict__ ss, const int* __restrict__ se) {
    __shared__ uint32_t lds_x[NWORDS * NIN];  // [w][i]   17 KB (transposed)
    __shared__ uint4    lds_pk[NG * 64];      // [g][hl]  16 KB {sp lo, sp hi, wq, pad}
    __shared__ float st_v[64];
    __shared__ float st_rf[64];
    __shared__ float st_sacc[KSLOT][64];      // authoritative (lazy relay)
    __shared__ int   flag;

    int bx = blockIdx.x;
    int hg = bx & 15;
    int b  = bx >> 4;
    int tid  = threadIdx.x;
    int lane = tid & 63;
    int sub  = tid >> 6;
    int hbase = hg * 64;

    for (int idx = tid; idx < NWORDS * NIN; idx += 512)
        lds_x[idx] = xbitsT[(size_t)b * NWORDS * NIN + idx];
    for (int idx = tid; idx < NG * 64; idx += 512) {
        int g = idx >> 6, hl = idx & 63;
        lds_pk[idx] = pk4[(size_t)g * NHID + hbase + hl];
    }
    if (tid < 64) { st_v[tid] = 0.0f; st_rf[tid] = 0.0f; }
    if (tid < KSLOT * 64) ((float*)st_sacc)[tid] = 0.0f;
    if (tid == 0) flag = 0;
    __syncthreads();

    int st_[KSLOT], en_[KSLOT];
    #pragma unroll
    for (int k = 0; k < KSLOT; ++k) {
        st_[k] = __builtin_amdgcn_readfirstlane(ss[k]);
        en_[k] = __builtin_amdgcn_readfirstlane(se[k]);
    }

    for (int rl = 0; rl < ROUNDS; ++rl) {
        int p  = __builtin_amdgcn_readfirstlane(rl * WAVES + sub);   // pair index 0..15
        int t0 = p * 64;
        int accL[32], accH[32];
        #pragma unroll
        for (int k = 0; k < 32; ++k) { accL[k] = 0; accH[k] = 0; }
        const uint32_t* xrow = lds_x + (2 * p) * NIN;   // rows 2p .. 2p+3 used
        #pragma unroll 1
        for (int g = 0; g < NG; ++g) {
            uint4 pkc = lds_pk[(g << 6) | lane];  // one ds_read_b128: {sp lo, sp hi, wq}
            uint32_t wq = pkc.z;
            uint32_t wl[8], wh[8];
            const uint32_t* xr = xrow + 8 * g;
            {   // half 0: streams 8g..8g+3 — 4 uniform b128 rows serve BOTH chunks
                uint4 r0 = *(const uint4*)(xr);
                uint4 r1 = *(const uint4*)(xr + NIN);
                uint4 r2 = *(const uint4*)(xr + 2 * NIN);
                uint4 r3 = *(const uint4*)(xr + 3 * NIN);
                BUILD4(pkc.x, r0, r1, r2, r3, wl, wh, 0)
            }
            {   // half 1: streams 8g+4..8g+7
                uint4 r0 = *(const uint4*)(xr + 4);
                uint4 r1 = *(const uint4*)(xr + NIN + 4);
                uint4 r2 = *(const uint4*)(xr + 2 * NIN + 4);
                uint4 r3 = *(const uint4*)(xr + 3 * NIN + 4);
                BUILD4(pkc.y, r0, r1, r2, r3, wl, wh, 4)
            }
            LADDER(wl, accL, wq)
            LADDER(wh, accH, wq)
        }
        // ---- pre-token: v-independent affine state (off the serial chain) ----
        float S = 0.0f, mS = -1e30f;
        PRES32(accL)
        PRES32(accH)
        // ---- relay: wait for token ----
        while (__builtin_amdgcn_readfirstlane(*(volatile int*)&flag) != p)
            __builtin_amdgcn_s_sleep(1);
        __builtin_amdgcn_s_setprio(1);
        float v  = st_v[lane];
        float rf = st_rf[lane];
        // sound spike test: true v_t <= max(v_in,0) + S_t + ~1e-6 <= max(v_in,0)+mS+1e-6
        bool slow = (rf > 0.0f) || (fmaxf(v, 0.0f) + mS >= 0.999f);
        if (__ballot(slow) != 0ULL) {
            // ---- exact path (rare: >=7 sigma margin) ----
            float sacc[KSLOT];
            #pragma unroll
            for (int k = 0; k < KSLOT; ++k) sacc[k] = st_sacc[k][lane];
            SLOW32(accL, t0)
            SLOW32(accH, t0 + 32)
            #pragma unroll
            for (int k = 0; k < KSLOT; ++k) st_sacc[k][lane] = sacc[k];
        } else {
            v = fmaf(P64, v, S);   // v_64 = 0.9^64 * v_in + S
            rf = 0.0f;
        }
        st_v[lane]  = v;
        st_rf[lane] = rf;
        __threadfence_block();                     // drain LDS writes before flag release
        if (lane == 0) *(volatile int*)&flag = p + 1;
        __builtin_amdgcn_s_setprio(0);
    }
    // ---- epilogue: after pair 15's relay write, LDS sacc is final ----
    if (sub == WAVES - 1) {
        float wr = w_ro[hbase + lane];
        #pragma unroll
        for (int k = 0; k < KSLOT; ++k) {
            float val = st_sacc[k][lane] * wr;
            #pragma unroll
            for (int o = 32; o > 0; o >>= 1) val += __shfl_down(val, o);
            if (lane == 0) atomicAdd(&out[b * KSLOT + k], val);
        }
    }
}

extern "C" void kernel_launch(void* const* d_in, const int* in_sizes, int n_in,
                              void* d_out, int out_size, void* d_ws, size_t ws_size,
                              hipStream_t stream) {
    const float* x   = (const float*)d_in[0];
    const float* W   = (const float*)d_in[1];
    const float* drw = (const float*)d_in[2];
    const float* wro = (const float*)d_in[3];
    const float* bro = (const float*)d_in[4];
    const int*   ss  = (const int*)d_in[5];
    const int*   se  = (const int*)d_in[6];
    float* out = (float*)d_out;

    uintptr_t base = (uintptr_t)d_ws;
    size_t off = 0;
    auto take = [&](size_t bytes) {
        size_t o = off;
        off = (off + bytes + 255) & ~(size_t)255;
        return (void*)(base + o);
    };
    uint32_t* xbitsT = (uint32_t*)take((size_t)B_DIM * NWORDS * NIN * 4);
    uint4*    pk4    = (uint4*)take((size_t)NG * NHID * 16);
    (void)ws_size;

    prep_kernel<<<581, 256, 0, stream>>>(x, W, drw, bro, xbitsT, pk4, out);
    fused_kernel<<<512, 512, 0, stream>>>(pk4, xbitsT, out, wro, ss, se);
}

// Round 6
// 153.959 us; speedup vs baseline: 1.0590x; 1.0590x over previous
//
#include <hip/hip_runtime.h>
#include <cstdint>

#define B_DIM 32
#define T_DIM 1024
#define NIN 128
#define NG 16       // i-groups of 8
#define NHID 1024
#define KSLOT 8
#define NWORDS 34   // 2 guard words (64 zero bits) + 32 data words
#define WAVES 8
#define CHUNKS 32
#define PAIRS (CHUNKS / 2)
#define ROUNDS (PAIRS / WAVES)
#define WSCALE 16.0f

// Incremental-mask ladder (R17): prefix masks {0x11,0x33,0x77,none}; per-t
// currents recovered by integer differencing (bit-exact vs bit-plane accs).
#define SC0 (1.0f / 16.0f)
#define SC1 (1.0f / 32.0f)
#define SC2 (1.0f / 64.0f)
#define SC3 (-1.0f / 128.0f)
// 0.9^64 (float-rounded); fast-path only, drift contracts x0.00118/pair
#define P64 0.0011790184577738599f

// 0.9^n, constant-folded at compile time (used only with unrolled-constant n)
constexpr float pw9(int n) {
    double r = 1.0;
    for (int i = 0; i < n; ++i) r *= 0.9;
    return (float)r;
}

// 8 x i4 MAC in one instruction (v_dot8_i32_i4). Fallback preserves semantics.
__device__ __forceinline__ int dot8acc(uint32_t sel, uint32_t wq, int acc) {
#if __has_builtin(__builtin_amdgcn_sdot8)
    return __builtin_amdgcn_sdot8((int)sel, (int)wq, acc, false);
#else
    #pragma unroll
    for (int m = 0; m < 8; ++m) {
        int s = ((int)((sel >> (4 * m)) & 0xF) << 28) >> 28;   // signed i4
        int q = ((int)((wq  >> (4 * m)) & 0xF) << 28) >> 28;   // signed i4
        acc += s * q;
    }
    return acc;
#endif
}

__device__ __forceinline__ uint32_t permb(uint32_t hi, uint32_t lo, uint32_t sel) {
#if __has_builtin(__builtin_amdgcn_perm)
    return __builtin_amdgcn_perm(hi, lo, sel);   // S0=hi(bytes 7..4), S1=lo(bytes 3..0)
#else
    union { uint32_t w[2]; unsigned char b[8]; } src;
    src.w[0] = lo; src.w[1] = hi;
    uint32_t r = 0;
    for (int n = 0; n < 4; ++n) r |= (uint32_t)src.b[(sel >> (8 * n)) & 7] << (8 * n);
    return r;
#endif
}

__device__ __forceinline__ uint32_t funnel32(uint32_t hi, uint32_t lo, uint32_t sh) {
#if __has_builtin(__builtin_amdgcn_alignbit)
    return __builtin_amdgcn_alignbit(hi, lo, sh);   // ((hi:lo) >> (sh&31)) low 32
#else
    return (uint32_t)(((((uint64_t)hi) << 32) | lo) >> (sh & 31));
#endif
}

// ---------------- merged prep kernel ----------------
// blocks   0..511: pack spike bits TRANSPOSED: xbitsT[b][w][i]
// blocks 512..575: packed per-(g,h) params: {sp bytes lo, sp bytes hi, wq nibbles, pad}
//                  (sp = 63 - delay; wq nibble order [0,4,1,5,2,6,3,7])
// blocks 576..580: init out (logits = bias, totals = 0)
__global__ void prep_kernel(const float* __restrict__ x, const float* __restrict__ W,
                            const float* __restrict__ draw, const float* __restrict__ b_ro,
                            uint32_t* __restrict__ xbitsT, uint4* __restrict__ pk4,
                            float* __restrict__ out) {
    int blk = blockIdx.x, tid = threadIdx.x;
    if (blk < 512) {
        int idx = blk * 256 + tid;        // 131072 = b*4096 + w*128 + i
        int b = idx >> 12, w = (idx >> 7) & 31, i = idx & 127;
        const float* xp = x + (size_t)b * T_DIM * NIN + (size_t)w * 32 * NIN + i;
        uint32_t word = 0;
        #pragma unroll
        for (int bit = 0; bit < 32; ++bit) {
            float xv = xp[(size_t)bit * NIN];   // lanes = consecutive i -> coalesced
            word |= (xv != 0.0f) ? (1u << bit) : 0u;
        }
        uint32_t* bp = xbitsT + (size_t)b * NWORDS * NIN;
        bp[(2 + w) * NIN + i] = word;           // transposed: [w][i]
        if (w == 0) { bp[i] = 0u; bp[NIN + i] = 0u; }   // guard rows
    } else if (blk < 576) {
        int idx = (blk - 512) * 256 + tid;    // 16384 = g*1024 + h
        int g = idx >> 10, h = idx & 1023;
        const float* Wp = W    + (size_t)h * NIN + 8 * g;
        const float* Rp = draw + (size_t)h * NIN + 8 * g;
        uint32_t s0 = 0, s1 = 0, wq = 0;
        const int ordm[8] = {0, 4, 1, 5, 2, 6, 3, 7};
        #pragma unroll
        for (int j = 0; j < 4; ++j) {
            int sp_a = 63 - (int)rintf(50.0f / (1.0f + expf(-Rp[j])));      // RNE = jnp.round
            int sp_b = 63 - (int)rintf(50.0f / (1.0f + expf(-Rp[4 + j])));
            s0 |= (uint32_t)sp_a << (8 * j);
            s1 |= (uint32_t)sp_b << (8 * j);
        }
        #pragma unroll
        for (int m = 0; m < 8; ++m) {
            int q = (int)rintf(fminf(fmaxf(Wp[ordm[m]] * WSCALE, -8.0f), 7.0f));
            wq |= ((uint32_t)q & 0xFu) << (4 * m);
        }
        pk4[(size_t)g * NHID + h] = make_uint4(s0, s1, wq, 0u);
    } else {
        int idx = (blk - 576) * 256 + tid;    // 1280 outputs
        if (idx < B_DIM * KSLOT) out[idx] = b_ro[0];
        else if (idx < B_DIM * KSLOT + T_DIM) out[idx] = 0.0f;
    }
}

// prefix-mask quad: 3 ands + 4 dots (was 4 ands + 4 dots)
#define QUAD4(X, ACC, BASE, WQ)                                                 \
    ACC[(BASE)+0] = dot8acc((X) & 0x11111111u, WQ, ACC[(BASE)+0]);              \
    ACC[(BASE)+1] = dot8acc((X) & 0x33333333u, WQ, ACC[(BASE)+1]);              \
    ACC[(BASE)+2] = dot8acc((X) & 0x77777777u, WQ, ACC[(BASE)+2]);              \
    ACC[(BASE)+3] = dot8acc((X),               WQ, ACC[(BASE)+3]);

// mask-ladder: 8 windows (one 32-t word per stream) -> 32 prefix dots via sdot8.
#define LADDER(W_, ACC, WQ)                                                     \
    {                                                                           \
        uint32_t A0 = permb(W_[1], W_[0], 0x05010400u);                         \
        uint32_t B0 = permb(W_[1], W_[0], 0x07030602u);                         \
        uint32_t C0 = permb(W_[3], W_[2], 0x05010400u);                         \
        uint32_t D0 = permb(W_[3], W_[2], 0x07030602u);                         \
        uint32_t A1 = permb(W_[5], W_[4], 0x05010400u);                         \
        uint32_t B1 = permb(W_[5], W_[4], 0x07030602u);                         \
        uint32_t C1 = permb(W_[7], W_[6], 0x05010400u);                         \
        uint32_t D1 = permb(W_[7], W_[6], 0x07030602u);                         \
        {                                                                       \
            uint32_t P = permb(C0, A0, 0x05040100u);                            \
            uint32_t Q = permb(C1, A1, 0x05040100u);                            \
            uint32_t X0 = (P & 0x0F0F0F0Fu) | ((Q << 4) & 0xF0F0F0F0u);         \
            uint32_t X1 = ((P >> 4) & 0x0F0F0F0Fu) | (Q & 0xF0F0F0F0u);         \
            QUAD4(X0, ACC, 0, WQ)                                               \
            QUAD4(X1, ACC, 4, WQ)                                               \
        }                                                                       \
        {                                                                       \
            uint32_t P = permb(C0, A0, 0x07060302u);                            \
            uint32_t Q = permb(C1, A1, 0x07060302u);                            \
            uint32_t X2 = (P & 0x0F0F0F0Fu) | ((Q << 4) & 0xF0F0F0F0u);         \
            uint32_t X3 = ((P >> 4) & 0x0F0F0F0Fu) | (Q & 0xF0F0F0F0u);         \
            QUAD4(X2, ACC, 8, WQ)                                               \
            QUAD4(X3, ACC, 12, WQ)                                              \
        }                                                                       \
        {                                                                       \
            uint32_t P = permb(D0, B0, 0x05040100u);                            \
            uint32_t Q = permb(D1, B1, 0x05040100u);                            \
            uint32_t X4 = (P & 0x0F0F0F0Fu) | ((Q << 4) & 0xF0F0F0F0u);         \
            uint32_t X5 = ((P >> 4) & 0x0F0F0F0Fu) | (Q & 0xF0F0F0F0u);         \
            QUAD4(X4, ACC, 16, WQ)                                              \
            QUAD4(X5, ACC, 20, WQ)                                              \
        }                                                                       \
        {                                                                       \
            uint32_t P = permb(D0, B0, 0x07060302u);                            \
            uint32_t Q = permb(D1, B1, 0x07060302u);                            \
            uint32_t X6 = (P & 0x0F0F0F0Fu) | ((Q << 4) & 0xF0F0F0F0u);         \
            uint32_t X7 = ((P >> 4) & 0x0F0F0F0Fu) | (Q & 0xF0F0F0F0u);         \
            QUAD4(X6, ACC, 24, WQ)                                              \
            QUAD4(X7, ACC, 28, WQ)                                              \
        }                                                                       \
    }

// build both pair-windows for 4 streams from 4 row-quads + packed sp byte word
#define BUILD4(SPW, R0, R1, R2, R3, WL, WH, BASE)                               \
    {                                                                           \
        uint32_t sp0 = (SPW) & 0xFFu;                                           \
        uint32_t sp1 = ((SPW) >> 8) & 0xFFu;                                    \
        uint32_t sp2 = ((SPW) >> 16) & 0xFFu;                                   \
        uint32_t sp3 = (SPW) >> 24;                                             \
        bool se0 = sp0 >= 32u, se1 = sp1 >= 32u, se2 = sp2 >= 32u, se3 = sp3 >= 32u; \
        uint32_t a0 = se0 ? R1.x : R0.x, m0 = se0 ? R2.x : R1.x, c0 = se0 ? R3.x : R2.x; \
        uint32_t a1 = se1 ? R1.y : R0.y, m1_ = se1 ? R2.y : R1.y, c1 = se1 ? R3.y : R2.y; \
        uint32_t a2 = se2 ? R1.z : R0.z, m2 = se2 ? R2.z : R1.z, c2 = se2 ? R3.z : R2.z; \
        uint32_t a3 = se3 ? R1.w : R0.w, m3 = se3 ? R2.w : R1.w, c3 = se3 ? R3.w : R2.w; \
        WL[BASE + 0] = funnel32(m0, a0, sp0);  WH[BASE + 0] = funnel32(c0, m0, sp0);  \
        WL[BASE + 1] = funnel32(m1_, a1, sp1); WH[BASE + 1] = funnel32(c1, m1_, sp1); \
        WL[BASE + 2] = funnel32(m2, a2, sp2);  WH[BASE + 2] = funnel32(c2, m2, sp2);  \
        WL[BASE + 3] = funnel32(m3, a3, sp3);  WH[BASE + 3] = funnel32(c3, m3, sp3);  \
    }

// pre-token affine envelope over one 32-acc half (R19):
// S_{k} = 0.9 S_{k-1} + 0.1 I_k (v-independent), mS = max_k S_k,
// m1 = max_k (0.9^k + S_k). Runs BEFORE the token -> off the serial chain.
// Chord bound (convexity of max-of-affine): vmax(v) <= mS + v*(m1-mS), v in [0,1).
#define PREV32(A, KOFF)                                                         \
    _Pragma("unroll")                                                           \
    for (int q = 0; q < 8; ++q) {                                               \
        int a0 = A[4*q], a1 = A[4*q+1], a2 = A[4*q+2], a3 = A[4*q+3];           \
        S = fmaf(0.9f, S, (float)a0        * (0.1f * SC0));                     \
        mS = fmaxf(mS, S); m1 = fmaxf(m1, S + pw9((KOFF) + 4*q + 1));           \
        S = fmaf(0.9f, S, (float)(a1 - a0) * (0.1f * SC1));                     \
        mS = fmaxf(mS, S); m1 = fmaxf(m1, S + pw9((KOFF) + 4*q + 2));           \
        S = fmaf(0.9f, S, (float)(a2 - a1) * (0.1f * SC2));                     \
        mS = fmaxf(mS, S); m1 = fmaxf(m1, S + pw9((KOFF) + 4*q + 3));           \
        S = fmaf(0.9f, S, (float)(a3 - a2) * (0.1f * SC3));                     \
        mS = fmaxf(mS, S); m1 = fmaxf(m1, S + pw9((KOFF) + 4*q + 4));           \
    }

// tier-2 exact replay over one 32-acc half: bit-identical recurrence to SLOW32
// (same source expression shape -> same codegen). Used only on bound trips.
#define FAST32(A)                                                               \
    _Pragma("unroll")                                                           \
    for (int q = 0; q < 8; ++q) {                                               \
        int a0 = A[4*q], a1 = A[4*q+1], a2 = A[4*q+2], a3 = A[4*q+3];           \
        float v0, v1, v2, v3;                                                   \
        vf += 0.1f * ((float)a0        * SC0 - vf); v0 = vf;                    \
        vf += 0.1f * ((float)(a1 - a0) * SC1 - vf); v1 = vf;                    \
        vf += 0.1f * ((float)(a2 - a1) * SC2 - vf); v2 = vf;                    \
        vf += 0.1f * ((float)(a3 - a2) * SC3 - vf); v3 = vf;                    \
        vmax = fmaxf(vmax, fmaxf(fmaxf(v0, v1), fmaxf(v2, v3)));                \
    }

// exact-path LIF over one 32-acc half (rare), prefix-diff recovery, bit-exact.
#define SLOW32(A, TBASE)                                                        \
    _Pragma("unroll")                                                           \
    for (int q = 0; q < 8; ++q) {                                               \
        int a0 = A[4*q], a1 = A[4*q+1], a2 = A[4*q+2], a3 = A[4*q+3];           \
        _Pragma("unroll")                                                       \
        for (int j = 0; j < 4; ++j) {                                           \
            float I = (j == 0) ? (float)a0        * SC0                         \
                    : (j == 1) ? (float)(a1 - a0) * SC1                         \
                    : (j == 2) ? (float)(a2 - a1) * SC2                         \
                    :            (float)(a3 - a2) * SC3;                        \
            int t = (TBASE) + 4 * q + j;                                        \
            bool active = (rf <= 0.0f);                                         \
            float vupd = v + 0.1f * (I - v);                                    \
            float vn = active ? vupd : v;                                       \
            bool spike = active && (vn >= 1.0f);                                \
            unsigned long long bal = __ballot(spike);                           \
            if (bal != 0ULL) {                                                  \
                if (spike) {                                                    \
                    vn = 0.0f;                /* V_RESET */                     \
                    _Pragma("unroll")                                           \
                    for (int k2 = 0; k2 < KSLOT; ++k2)                          \
                        if (t >= st_[k2] && t < en_[k2]) sacc[k2] += 1.0f;      \
                }                                                               \
                rf = spike ? 2.0f : fmaxf(rf - 1.0f, 0.0f);                     \
                if (lane == 0) atomicAdd(&out[B_DIM * KSLOT + t], (float)__popcll(bal)); \
            } else {                                                            \
                rf = fmaxf(rf - 1.0f, 0.0f);                                    \
            }                                                                   \
            v = vn;                                                             \
        }                                                                       \
    }

// ---------------- fused sdot8 mask-ladder + wave-relay LIF ----------------
// block = (b, hg of 64 h), 512 threads = 8 waves, grid 512.
// R19 = R17 (81 us) + affine hoist with CHORD bound + 3-tier fallback.
// R18 post-mortem: mS-only bound (max(v,0)+mS) decouples v-decay from S-peak
// -> frequent false positives -> whole wave into SLOW32 (64 serial ballots)
// INSIDE the token-critical section -> chain lengthened, 81->96 us, VALUBusy
// 74->64. Fix: vmax(v) = max_k(0.9^k v + S_k) is convex increasing in v; for
// v in [0,1): vmax <= mS + v*(m1-mS) (chord through env(0)=mS, env(1)=m1).
// Strictly tighter than R18 (which is the chord with m1 -> 1+mS). Tiering:
// bound trip -> exact FAST32 replay in-section (== R17 link cost, bit-exact
// to SLOW32) -> SLOW32 only on true spike/refractory. Worst case == R17.
// Invariant: fast path keeps v < 0.999 < 1, so v in [0,1) holds entering
// every round. Drift margin: bound fp error + per-step-vs-affine drift
// ~4e-6 << 1e-3 threshold margin. setprio dropped (R18 confounder).
__global__ __launch_bounds__(512, 4) void fused_kernel(
    const uint4* __restrict__ pk4, const uint32_t* __restrict__ xbitsT,
    float* __restrict__ out, const float* __restrict__ w_ro,
    const int* __restrict__ ss, const int* __restrict__ se) {
    __shared__ uint32_t lds_x[NWORDS * NIN];  // [w][i]   17 KB (transposed)
    __shared__ uint4    lds_pk[NG * 64];      // [g][hl]  16 KB {sp lo, sp hi, wq, pad}
    __shared__ float st_v[64];
    __shared__ float st_rf[64];
    __shared__ float st_sacc[KSLOT][64];      // authoritative (lazy relay)
    __shared__ int   flag;

    int bx = blockIdx.x;
    int hg = bx & 15;
    int b  = bx >> 4;
    int tid  = threadIdx.x;
    int lane = tid & 63;
    int sub  = tid >> 6;
    int hbase = hg * 64;

    for (int idx = tid; idx < NWORDS * NIN; idx += 512)
        lds_x[idx] = xbitsT[(size_t)b * NWORDS * NIN + idx];
    for (int idx = tid; idx < NG * 64; idx += 512) {
        int g = idx >> 6, hl = idx & 63;
        lds_pk[idx] = pk4[(size_t)g * NHID + hbase + hl];
    }
    if (tid < 64) { st_v[tid] = 0.0f; st_rf[tid] = 0.0f; }
    if (tid < KSLOT * 64) ((float*)st_sacc)[tid] = 0.0f;
    if (tid == 0) flag = 0;
    __syncthreads();

    int st_[KSLOT], en_[KSLOT];
    #pragma unroll
    for (int k = 0; k < KSLOT; ++k) {
        st_[k] = __builtin_amdgcn_readfirstlane(ss[k]);
        en_[k] = __builtin_amdgcn_readfirstlane(se[k]);
    }

    for (int rl = 0; rl < ROUNDS; ++rl) {
        int p  = __builtin_amdgcn_readfirstlane(rl * WAVES + sub);   // pair index 0..15
        int t0 = p * 64;
        int accL[32], accH[32];
        #pragma unroll
        for (int k = 0; k < 32; ++k) { accL[k] = 0; accH[k] = 0; }
        const uint32_t* xrow = lds_x + (2 * p) * NIN;   // rows 2p .. 2p+3 used
        #pragma unroll 1
        for (int g = 0; g < NG; ++g) {
            uint4 pkc = lds_pk[(g << 6) | lane];  // one ds_read_b128: {sp lo, sp hi, wq}
            uint32_t wq = pkc.z;
            uint32_t wl[8], wh[8];
            const uint32_t* xr = xrow + 8 * g;
            {   // half 0: streams 8g..8g+3 — 4 uniform b128 rows serve BOTH chunks
                uint4 r0 = *(const uint4*)(xr);
                uint4 r1 = *(const uint4*)(xr + NIN);
                uint4 r2 = *(const uint4*)(xr + 2 * NIN);
                uint4 r3 = *(const uint4*)(xr + 3 * NIN);
                BUILD4(pkc.x, r0, r1, r2, r3, wl, wh, 0)
            }
            {   // half 1: streams 8g+4..8g+7
                uint4 r0 = *(const uint4*)(xr + 4);
                uint4 r1 = *(const uint4*)(xr + NIN + 4);
                uint4 r2 = *(const uint4*)(xr + 2 * NIN + 4);
                uint4 r3 = *(const uint4*)(xr + 3 * NIN + 4);
                BUILD4(pkc.y, r0, r1, r2, r3, wl, wh, 4)
            }
            LADDER(wl, accL, wq)
            LADDER(wh, accH, wq)
        }
        // ---- pre-token: v-independent affine envelope (off the serial chain) ----
        float S = 0.0f, mS = -1e30f, m1 = -1e30f;
        PREV32(accL, 0)
        PREV32(accH, 32)
        float dm = m1 - mS;   // > 0 always (0.9^k > 0)
        // ---- relay: wait for token ----
        while (__builtin_amdgcn_readfirstlane(*(volatile int*)&flag) != p)
            __builtin_amdgcn_s_sleep(1);
        float v  = st_v[lane];
        float rf = st_rf[lane];
        float vc = fmaxf(v, 0.0f);
        bool trip = (rf > 0.0f) || (fmaf(vc, dm, mS) >= 0.999f);
        if (__ballot(trip) != 0ULL) {
            // ---- tier 2: exact replay (only on bound trip; == R17 link cost) ----
            bool do_slow = true;
            float vf = v;
            if (__ballot(rf > 0.0f) == 0ULL) {
                float vmax = -1.0f;
                FAST32(accL)
                FAST32(accH)
                do_slow = (__ballot(vmax >= 1.0f) != 0ULL);
            }
            if (do_slow) {
                // ---- tier 3: true spike / refractory — bit-exact state machine ----
                float sacc[KSLOT];
                #pragma unroll
                for (int k = 0; k < KSLOT; ++k) sacc[k] = st_sacc[k][lane];
                SLOW32(accL, t0)
                SLOW32(accH, t0 + 32)
                #pragma unroll
                for (int k = 0; k < KSLOT; ++k) st_sacc[k][lane] = sacc[k];
            } else {
                v = vf;              // exact trajectory endpoint, no spike
                rf = 0.0f;
            }
        } else {
            v = fmaf(P64, v, S);     // v_64 = 0.9^64 * v_in + S_64
            rf = 0.0f;
        }
        st_v[lane]  = v;
        st_rf[lane] = rf;
        __threadfence_block();                     // drain LDS writes before flag release
        if (lane == 0) *(volatile int*)&flag = p + 1;
    }
    // ---- epilogue: after pair 15's relay write, LDS sacc is final ----
    if (sub == WAVES - 1) {
        float wr = w_ro[hbase + lane];
        #pragma unroll
        for (int k = 0; k < KSLOT; ++k) {
            float val = st_sacc[k][lane] * wr;
            #pragma unroll
            for (int o = 32; o > 0; o >>= 1) val += __shfl_down(val, o);
            if (lane == 0) atomicAdd(&out[b * KSLOT + k], val);
        }
    }
}

extern "C" void kernel_launch(void* const* d_in, const int* in_sizes, int n_in,
                              void* d_out, int out_size, void* d_ws, size_t ws_size,
                              hipStream_t stream) {
    const float* x   = (const float*)d_in[0];
    const float* W   = (const float*)d_in[1];
    const float* drw = (const float*)d_in[2];
    const float* wro = (const float*)d_in[3];
    const float* bro = (const float*)d_in[4];
    const int*   ss  = (const int*)d_in[5];
    const int*   se  = (const int*)d_in[6];
    float* out = (float*)d_out;

    uintptr_t base = (uintptr_t)d_ws;
    size_t off = 0;
    auto take = [&](size_t bytes) {
        size_t o = off;
        off = (off + bytes + 255) & ~(size_t)255;
        return (void*)(base + o);
    };
    uint32_t* xbitsT = (uint32_t*)take((size_t)B_DIM * NWORDS * NIN * 4);
    uint4*    pk4    = (uint4*)take((size_t)NG * NHID * 16);
    (void)ws_size;

    prep_kernel<<<581, 256, 0, stream>>>(x, W, drw, bro, xbitsT, pk4, out);
    fused_kernel<<<512, 512, 0, stream>>>(pk4, xbitsT, out, wro, ss, se);
}

// Round 7
// 149.960 us; speedup vs baseline: 1.0872x; 1.0267x over previous
//
#include <hip/hip_runtime.h>
#include <cstdint>

#define B_DIM 32
#define T_DIM 1024
#define NIN 128
#define NG 16       // i-groups of 8
#define NHID 1024
#define KSLOT 8
#define NWORDS 34   // 2 guard words (64 zero bits) + 32 data words
#define WAVES 8
#define CHUNKS 32
#define PAIRS (CHUNKS / 2)
#define ROUNDS (PAIRS / WAVES)
#define WSCALE 16.0f

// Incremental-mask ladder (R17): prefix masks {0x11,0x33,0x77,none}; per-t
// currents recovered by integer differencing (bit-exact vs bit-plane accs).
#define SC0 (1.0f / 16.0f)
#define SC1 (1.0f / 32.0f)
#define SC2 (1.0f / 64.0f)
#define SC3 (-1.0f / 128.0f)

// 8 x i4 MAC in one instruction (v_dot8_i32_i4). Fallback preserves semantics.
__device__ __forceinline__ int dot8acc(uint32_t sel, uint32_t wq, int acc) {
#if __has_builtin(__builtin_amdgcn_sdot8)
    return __builtin_amdgcn_sdot8((int)sel, (int)wq, acc, false);
#else
    #pragma unroll
    for (int m = 0; m < 8; ++m) {
        int s = ((int)((sel >> (4 * m)) & 0xF) << 28) >> 28;   // signed i4
        int q = ((int)((wq  >> (4 * m)) & 0xF) << 28) >> 28;   // signed i4
        acc += s * q;
    }
    return acc;
#endif
}

__device__ __forceinline__ uint32_t permb(uint32_t hi, uint32_t lo, uint32_t sel) {
#if __has_builtin(__builtin_amdgcn_perm)
    return __builtin_amdgcn_perm(hi, lo, sel);   // S0=hi(bytes 7..4), S1=lo(bytes 3..0)
#else
    union { uint32_t w[2]; unsigned char b[8]; } src;
    src.w[0] = lo; src.w[1] = hi;
    uint32_t r = 0;
    for (int n = 0; n < 4; ++n) r |= (uint32_t)src.b[(sel >> (8 * n)) & 7] << (8 * n);
    return r;
#endif
}

__device__ __forceinline__ uint32_t funnel32(uint32_t hi, uint32_t lo, uint32_t sh) {
#if __has_builtin(__builtin_amdgcn_alignbit)
    return __builtin_amdgcn_alignbit(hi, lo, sh);   // ((hi:lo) >> (sh&31)) low 32
#else
    return (uint32_t)(((((uint64_t)hi) << 32) | lo) >> (sh & 31));
#endif
}

// ---------------- merged prep kernel ----------------
// blocks   0..511: pack spike bits TRANSPOSED: xbitsT[b][w][i]
// blocks 512..575: packed per-(g,h) params: {sp bytes lo, sp bytes hi, wq nibbles, pad}
//                  (sp = 63 - delay; wq nibble order [0,4,1,5,2,6,3,7])
// blocks 576..580: init out (logits = bias, totals = 0)
__global__ void prep_kernel(const float* __restrict__ x, const float* __restrict__ W,
                            const float* __restrict__ draw, const float* __restrict__ b_ro,
                            uint32_t* __restrict__ xbitsT, uint4* __restrict__ pk4,
                            float* __restrict__ out) {
    int blk = blockIdx.x, tid = threadIdx.x;
    if (blk < 512) {
        int idx = blk * 256 + tid;        // 131072 = b*4096 + w*128 + i
        int b = idx >> 12, w = (idx >> 7) & 31, i = idx & 127;
        const float* xp = x + (size_t)b * T_DIM * NIN + (size_t)w * 32 * NIN + i;
        uint32_t word = 0;
        #pragma unroll
        for (int bit = 0; bit < 32; ++bit) {
            float xv = xp[(size_t)bit * NIN];   // lanes = consecutive i -> coalesced
            word |= (xv != 0.0f) ? (1u << bit) : 0u;
        }
        uint32_t* bp = xbitsT + (size_t)b * NWORDS * NIN;
        bp[(2 + w) * NIN + i] = word;           // transposed: [w][i]
        if (w == 0) { bp[i] = 0u; bp[NIN + i] = 0u; }   // guard rows
    } else if (blk < 576) {
        int idx = (blk - 512) * 256 + tid;    // 16384 = g*1024 + h
        int g = idx >> 10, h = idx & 1023;
        const float* Wp = W    + (size_t)h * NIN + 8 * g;
        const float* Rp = draw + (size_t)h * NIN + 8 * g;
        uint32_t s0 = 0, s1 = 0, wq = 0;
        const int ordm[8] = {0, 4, 1, 5, 2, 6, 3, 7};
        #pragma unroll
        for (int j = 0; j < 4; ++j) {
            int sp_a = 63 - (int)rintf(50.0f / (1.0f + expf(-Rp[j])));      // RNE = jnp.round
            int sp_b = 63 - (int)rintf(50.0f / (1.0f + expf(-Rp[4 + j])));
            s0 |= (uint32_t)sp_a << (8 * j);
            s1 |= (uint32_t)sp_b << (8 * j);
        }
        #pragma unroll
        for (int m = 0; m < 8; ++m) {
            int q = (int)rintf(fminf(fmaxf(Wp[ordm[m]] * WSCALE, -8.0f), 7.0f));
            wq |= ((uint32_t)q & 0xFu) << (4 * m);
        }
        pk4[(size_t)g * NHID + h] = make_uint4(s0, s1, wq, 0u);
    } else {
        int idx = (blk - 576) * 256 + tid;    // 1280 outputs
        if (idx < B_DIM * KSLOT) out[idx] = b_ro[0];
        else if (idx < B_DIM * KSLOT + T_DIM) out[idx] = 0.0f;
    }
}

// prefix-mask quad: 3 ands + 4 dots (was 4 ands + 4 dots)
#define QUAD4(X, ACC, BASE, WQ)                                                 \
    ACC[(BASE)+0] = dot8acc((X) & 0x11111111u, WQ, ACC[(BASE)+0]);              \
    ACC[(BASE)+1] = dot8acc((X) & 0x33333333u, WQ, ACC[(BASE)+1]);              \
    ACC[(BASE)+2] = dot8acc((X) & 0x77777777u, WQ, ACC[(BASE)+2]);              \
    ACC[(BASE)+3] = dot8acc((X),               WQ, ACC[(BASE)+3]);

// mask-ladder: 8 windows (one 32-t word per stream) -> 32 prefix dots via sdot8.
// X-mix expressions kept in ((a&M)|(b&~M)) form for v_bfi_b32 pattern-match.
#define LADDER(W_, ACC, WQ)                                                     \
    {                                                                           \
        uint32_t A0 = permb(W_[1], W_[0], 0x05010400u);                         \
        uint32_t B0 = permb(W_[1], W_[0], 0x07030602u);                         \
        uint32_t C0 = permb(W_[3], W_[2], 0x05010400u);                         \
        uint32_t D0 = permb(W_[3], W_[2], 0x07030602u);                         \
        uint32_t A1 = permb(W_[5], W_[4], 0x05010400u);                         \
        uint32_t B1 = permb(W_[5], W_[4], 0x07030602u);                         \
        uint32_t C1 = permb(W_[7], W_[6], 0x05010400u);                         \
        uint32_t D1 = permb(W_[7], W_[6], 0x07030602u);                         \
        {                                                                       \
            uint32_t P = permb(C0, A0, 0x05040100u);                            \
            uint32_t Q = permb(C1, A1, 0x05040100u);                            \
            uint32_t X0 = (P & 0x0F0F0F0Fu) | ((Q << 4) & 0xF0F0F0F0u);         \
            uint32_t X1 = ((P >> 4) & 0x0F0F0F0Fu) | (Q & 0xF0F0F0F0u);         \
            QUAD4(X0, ACC, 0, WQ)                                               \
            QUAD4(X1, ACC, 4, WQ)                                               \
        }                                                                       \
        {                                                                       \
            uint32_t P = permb(C0, A0, 0x07060302u);                            \
            uint32_t Q = permb(C1, A1, 0x07060302u);                            \
            uint32_t X2 = (P & 0x0F0F0F0Fu) | ((Q << 4) & 0xF0F0F0F0u);         \
            uint32_t X3 = ((P >> 4) & 0x0F0F0F0Fu) | (Q & 0xF0F0F0F0u);         \
            QUAD4(X2, ACC, 8, WQ)                                               \
            QUAD4(X3, ACC, 12, WQ)                                              \
        }                                                                       \
        {                                                                       \
            uint32_t P = permb(D0, B0, 0x05040100u);                            \
            uint32_t Q = permb(D1, B1, 0x05040100u);                            \
            uint32_t X4 = (P & 0x0F0F0F0Fu) | ((Q << 4) & 0xF0F0F0F0u);         \
            uint32_t X5 = ((P >> 4) & 0x0F0F0F0Fu) | (Q & 0xF0F0F0F0u);         \
            QUAD4(X4, ACC, 16, WQ)                                              \
            QUAD4(X5, ACC, 20, WQ)                                              \
        }                                                                       \
        {                                                                       \
            uint32_t P = permb(D0, B0, 0x07060302u);                            \
            uint32_t Q = permb(D1, B1, 0x07060302u);                            \
            uint32_t X6 = (P & 0x0F0F0F0Fu) | ((Q << 4) & 0xF0F0F0F0u);         \
            uint32_t X7 = ((P >> 4) & 0x0F0F0F0Fu) | (Q & 0xF0F0F0F0u);         \
            QUAD4(X6, ACC, 24, WQ)                                              \
            QUAD4(X7, ACC, 28, WQ)                                              \
        }                                                                       \
    }

// build both pair-windows for 4 streams from 4 row-quads + packed sp byte word
#define BUILD4(SPW, R0, R1, R2, R3, WL, WH, BASE)                               \
    {                                                                           \
        uint32_t sp0 = (SPW) & 0xFFu;                                           \
        uint32_t sp1 = ((SPW) >> 8) & 0xFFu;                                    \
        uint32_t sp2 = ((SPW) >> 16) & 0xFFu;                                   \
        uint32_t sp3 = (SPW) >> 24;                                             \
        bool se0 = sp0 >= 32u, se1 = sp1 >= 32u, se2 = sp2 >= 32u, se3 = sp3 >= 32u; \
        uint32_t a0 = se0 ? R1.x : R0.x, m0 = se0 ? R2.x : R1.x, c0 = se0 ? R3.x : R2.x; \
        uint32_t a1 = se1 ? R1.y : R0.y, m1 = se1 ? R2.y : R1.y, c1 = se1 ? R3.y : R2.y; \
        uint32_t a2 = se2 ? R1.z : R0.z, m2 = se2 ? R2.z : R1.z, c2 = se2 ? R3.z : R2.z; \
        uint32_t a3 = se3 ? R1.w : R0.w, m3 = se3 ? R2.w : R1.w, c3 = se3 ? R3.w : R2.w; \
        WL[BASE + 0] = funnel32(m0, a0, sp0); WH[BASE + 0] = funnel32(c0, m0, sp0); \
        WL[BASE + 1] = funnel32(m1, a1, sp1); WH[BASE + 1] = funnel32(c1, m1, sp1); \
        WL[BASE + 2] = funnel32(m2, a2, sp2); WH[BASE + 2] = funnel32(c2, m2, sp2); \
        WL[BASE + 3] = funnel32(m3, a3, sp3); WH[BASE + 3] = funnel32(c3, m3, sp3); \
    }

// fast-path LIF over one 32-acc half with prefix-diff current recovery.
// I values bit-exact vs old bit-plane accs: a1-a0 == old 2*A1 etc.
#define FAST32(A)                                                               \
    _Pragma("unroll")                                                           \
    for (int q = 0; q < 8; ++q) {                                               \
        int a0 = A[4*q], a1 = A[4*q+1], a2 = A[4*q+2], a3 = A[4*q+3];           \
        float v0, v1, v2, v3;                                                   \
        vf += 0.1f * ((float)a0        * SC0 - vf); v0 = vf;                    \
        vf += 0.1f * ((float)(a1 - a0) * SC1 - vf); v1 = vf;                    \
        vf += 0.1f * ((float)(a2 - a1) * SC2 - vf); v2 = vf;                    \
        vf += 0.1f * ((float)(a3 - a2) * SC3 - vf); v3 = vf;                    \
        vmax = fmaxf(vmax, fmaxf(fmaxf(v0, v1), fmaxf(v2, v3)));                \
    }

// exact-path LIF over one 32-acc half (rare), same prefix-diff recovery.
#define SLOW32(A, TBASE)                                                        \
    _Pragma("unroll")                                                           \
    for (int q = 0; q < 8; ++q) {                                               \
        int a0 = A[4*q], a1 = A[4*q+1], a2 = A[4*q+2], a3 = A[4*q+3];           \
        _Pragma("unroll")                                                       \
        for (int j = 0; j < 4; ++j) {                                           \
            float I = (j == 0) ? (float)a0        * SC0                         \
                    : (j == 1) ? (float)(a1 - a0) * SC1                         \
                    : (j == 2) ? (float)(a2 - a1) * SC2                         \
                    :            (float)(a3 - a2) * SC3;                        \
            int t = (TBASE) + 4 * q + j;                                        \
            bool active = (rf <= 0.0f);                                         \
            float vupd = v + 0.1f * (I - v);                                    \
            float vn = active ? vupd : v;                                       \
            bool spike = active && (vn >= 1.0f);                                \
            unsigned long long bal = __ballot(spike);                           \
            if (bal != 0ULL) {                                                  \
                if (spike) {                                                    \
                    vn = 0.0f;                /* V_RESET */                     \
                    _Pragma("unroll")                                           \
                    for (int k2 = 0; k2 < KSLOT; ++k2)                          \
                        if (t >= st_[k2] && t < en_[k2]) sacc[k2] += 1.0f;      \
                }                                                               \
                rf = spike ? 2.0f : fmaxf(rf - 1.0f, 0.0f);                     \
                if (lane == 0) atomicAdd(&out[B_DIM * KSLOT + t], (float)__popcll(bal)); \
            } else {                                                            \
                rf = fmaxf(rf - 1.0f, 0.0f);                                    \
            }                                                                   \
            v = vn;                                                             \
        }                                                                       \
    }

// ---------------- fused sdot8 mask-ladder + wave-relay LIF ----------------
// block = (b, hg of 64 h), 512 threads = 8 waves, grid 512.
// R20 = exact revert to R17 (session best: 81.0 us fused / 149.25 us total).
// R18 (affine hoist, mS bound) regressed 81->96: loose bound -> wave-wide
// SLOW32 in the critical section. R19 (chord bound + tiers) regressed 81->85:
// trip rate ~0 but PREV32's envelope tracking added ~350 pre-token ops/pair
// vs the ~280-op FAST32 it displaced. Both falsify the "relay chain dominates"
// theory: the 8 waves are time-skewed by dot work, so FAST32-in-critical was
// already overlapped. Evidence stack: R14 occupancy x2 neutral; R16 ILP
// neutral; R15/R17/R19 time tracks total issued instructions ~1:1. The
// structure is issue-bound at ~74% VALU issue; residual is DS-issue/waitcnt/
// bookkeeping. Candidate cuts audited and rejected: quad fusion (acc VGPR
// blowup -> spill/occupancy cliff), per-lane ds_read windows (more issue
// slots), 96-bit funnel restructure (same count), MFMA i8 (gather/pack >=
// window cost). Practical roofline of this formulation.
__global__ __launch_bounds__(512, 4) void fused_kernel(
    const uint4* __restrict__ pk4, const uint32_t* __restrict__ xbitsT,
    float* __restrict__ out, const float* __restrict__ w_ro,
    const int* __restrict__ ss, const int* __restrict__ se) {
    __shared__ uint32_t lds_x[NWORDS * NIN];  // [w][i]   17 KB (transposed)
    __shared__ uint4    lds_pk[NG * 64];      // [g][hl]  16 KB {sp lo, sp hi, wq, pad}
    __shared__ float st_v[64];
    __shared__ float st_rf[64];
    __shared__ float st_sacc[KSLOT][64];      // authoritative (lazy relay)
    __shared__ int   flag;

    int bx = blockIdx.x;
    int hg = bx & 15;
    int b  = bx >> 4;
    int tid  = threadIdx.x;
    int lane = tid & 63;
    int sub  = tid >> 6;
    int hbase = hg * 64;

    for (int idx = tid; idx < NWORDS * NIN; idx += 512)
        lds_x[idx] = xbitsT[(size_t)b * NWORDS * NIN + idx];
    for (int idx = tid; idx < NG * 64; idx += 512) {
        int g = idx >> 6, hl = idx & 63;
        lds_pk[idx] = pk4[(size_t)g * NHID + hbase + hl];
    }
    if (tid < 64) { st_v[tid] = 0.0f; st_rf[tid] = 0.0f; }
    if (tid < KSLOT * 64) ((float*)st_sacc)[tid] = 0.0f;
    if (tid == 0) flag = 0;
    __syncthreads();

    int st_[KSLOT], en_[KSLOT];
    #pragma unroll
    for (int k = 0; k < KSLOT; ++k) {
        st_[k] = __builtin_amdgcn_readfirstlane(ss[k]);
        en_[k] = __builtin_amdgcn_readfirstlane(se[k]);
    }

    for (int rl = 0; rl < ROUNDS; ++rl) {
        int p  = __builtin_amdgcn_readfirstlane(rl * WAVES + sub);   // pair index 0..15
        int t0 = p * 64;
        int accL[32], accH[32];
        #pragma unroll
        for (int k = 0; k < 32; ++k) { accL[k] = 0; accH[k] = 0; }
        const uint32_t* xrow = lds_x + (2 * p) * NIN;   // rows 2p .. 2p+3 used
        #pragma unroll 1
        for (int g = 0; g < NG; ++g) {
            uint4 pkc = lds_pk[(g << 6) | lane];  // one ds_read_b128: {sp lo, sp hi, wq}
            uint32_t wq = pkc.z;
            uint32_t wl[8], wh[8];
            const uint32_t* xr = xrow + 8 * g;
            {   // half 0: streams 8g..8g+3 — 4 uniform b128 rows serve BOTH chunks
                uint4 r0 = *(const uint4*)(xr);
                uint4 r1 = *(const uint4*)(xr + NIN);
                uint4 r2 = *(const uint4*)(xr + 2 * NIN);
                uint4 r3 = *(const uint4*)(xr + 3 * NIN);
                BUILD4(pkc.x, r0, r1, r2, r3, wl, wh, 0)
            }
            {   // half 1: streams 8g+4..8g+7
                uint4 r0 = *(const uint4*)(xr + 4);
                uint4 r1 = *(const uint4*)(xr + NIN + 4);
                uint4 r2 = *(const uint4*)(xr + 2 * NIN + 4);
                uint4 r3 = *(const uint4*)(xr + 3 * NIN + 4);
                BUILD4(pkc.y, r0, r1, r2, r3, wl, wh, 4)
            }
            LADDER(wl, accL, wq)
            LADDER(wh, accH, wq)
        }
        // ---- relay: wait for token ----
        while (__builtin_amdgcn_readfirstlane(*(volatile int*)&flag) != p)
            __builtin_amdgcn_s_sleep(1);
        float v  = st_v[lane];
        float rf = st_rf[lane];
        // ---- LIF fast path over 64 steps (exact detection of slow-path need) ----
        float vf = v, vmax = -1.0f;
        FAST32(accL)
        FAST32(accH)
        bool slow = (rf > 0.0f) || (vmax >= 1.0f);
        if (__ballot(slow) != 0ULL) {
            // ---- exact path (rare: >=7 sigma margin) ----
            float sacc[KSLOT];
            #pragma unroll
            for (int k = 0; k < KSLOT; ++k) sacc[k] = st_sacc[k][lane];
            SLOW32(accL, t0)
            SLOW32(accH, t0 + 32)
            #pragma unroll
            for (int k = 0; k < KSLOT; ++k) st_sacc[k][lane] = sacc[k];
        } else {
            v = vf;
            rf = 0.0f;
        }
        st_v[lane]  = v;
        st_rf[lane] = rf;
        __threadfence_block();                     // drain LDS writes before flag release
        if (lane == 0) *(volatile int*)&flag = p + 1;
    }
    // ---- epilogue: after pair 15's relay write, LDS sacc is final ----
    if (sub == WAVES - 1) {
        float wr = w_ro[hbase + lane];
        #pragma unroll
        for (int k = 0; k < KSLOT; ++k) {
            float val = st_sacc[k][lane] * wr;
            #pragma unroll
            for (int o = 32; o > 0; o >>= 1) val += __shfl_down(val, o);
            if (lane == 0) atomicAdd(&out[b * KSLOT + k], val);
        }
    }
}

extern "C" void kernel_launch(void* const* d_in, const int* in_sizes, int n_in,
                              void* d_out, int out_size, void* d_ws, size_t ws_size,
                              hipStream_t stream) {
    const float* x   = (const float*)d_in[0];
    const float* W   = (const float*)d_in[1];
    const float* drw = (const float*)d_in[2];
    const float* wro = (const float*)d_in[3];
    const float* bro = (const float*)d_in[4];
    const int*   ss  = (const int*)d_in[5];
    const int*   se  = (const int*)d_in[6];
    float* out = (float*)d_out;

    uintptr_t base = (uintptr_t)d_ws;
    size_t off = 0;
    auto take = [&](size_t bytes) {
        size_t o = off;
        off = (off + bytes + 255) & ~(size_t)255;
        return (void*)(base + o);
    };
    uint32_t* xbitsT = (uint32_t*)take((size_t)B_DIM * NWORDS * NIN * 4);
    uint4*    pk4    = (uint4*)take((size_t)NG * NHID * 16);
    (void)ws_size;

    prep_kernel<<<581, 256, 0, stream>>>(x, W, drw, bro, xbitsT, pk4, out);
    fused_kernel<<<512, 512, 0, stream>>>(pk4, xbitsT, out, wro, ss, se);
}